// Round 14
// baseline (1077.848 us; speedup 1.0000x reference)
//
#include <hip/hip_runtime.h>

typedef unsigned short u16;
typedef unsigned int   u32;
typedef u16   u16x4 __attribute__((ext_vector_type(4)));
typedef u16   u16x8 __attribute__((ext_vector_type(8)));
typedef short s16x8 __attribute__((ext_vector_type(8)));
typedef u32   u32x4 __attribute__((ext_vector_type(4)));
typedef int   s32x4 __attribute__((ext_vector_type(4)));
typedef float f32x4 __attribute__((ext_vector_type(4)));

// ---------- bf16 helpers (bit-level, RNE) ----------
__device__ __forceinline__ float bf2f(u16 u) {
    u32 x = ((u32)u) << 16;
    return __builtin_bit_cast(float, x);
}
__device__ __forceinline__ u16 f2bf(float f) {
    u32 u = __builtin_bit_cast(u32, f);
    u32 r = u + 0x7FFFu + ((u >> 16) & 1u);
    return (u16)(r >> 16);
}
// packed f32x2 -> bf16x2 (RNE), lo = src0
__device__ __forceinline__ u32 cvtpk(float a, float b) {
    u32 r;
    asm("v_cvt_pk_bf16_f32 %0, %1, %2" : "=v"(r) : "v"(a), "v"(b));
    return r;
}

// async global->LDS, 16B per lane; lds dest is wave-uniform base (HW: base + lane*16)
__device__ __forceinline__ void gload16(const void* g, void* lds) {
    __builtin_amdgcn_global_load_lds((const __attribute__((address_space(1))) void*)g,
                                     (__attribute__((address_space(3))) void*)lds, 16, 0, 0);
}

// ---------- sizes ----------
#define TOT   16384      // BS*N nodes
#define HID   512
#define NRELS 8
#define EDGES 262144
#define INDIM 3072
#define NOUT  128
#define NGRAPH 16
#define NODESPER 1024
#define EKSPLIT 4        // ELMo split-K: 768 per block, 12 k-steps

// workspace layout (16B aligned)
#define OFF_XB     ((size_t)0)                    // u16 [16384][512]   16,777,216 B
#define OFF_Y      (OFF_XB + 16777216)            // u16 [16384][4096] 134,217,728 B (also ELMo bf16 partials [4][16384][256] = 33.5 MB)
#define OFF_WCT    (OFF_Y + 134217728)            // u16 [4096][512]     4,194,304 B
#define OFF_WET    (OFF_WCT + 4194304)            // u16 [256][3072]     1,572,864 B
#define OFF_CNT    (OFF_WET + 1572864)            // int [16384]
#define OFF_ROWPTR (OFF_CNT + 65536)              // int [16385] (+pad)
#define OFF_CURSOR (OFF_ROWPTR + 65552)           // int [16384]
#define OFF_EPK    (OFF_CURSOR + 65536)           // int [262144]
#define OFF_ENORM  (OFF_EPK + 1048576)            // float [262144]
#define OFF_PART   (OFF_ENORM + 1048576)          // float [256][512]

// ---------- prep: WcatT[(r*512+n)][k] = sum_b comp[r,b] * V[b][k][n] ----------
// one block computes one 64x64 (k,n) tile for ALL 8 relations -> V read once (8.4 MB total)
__global__ __launch_bounds__(256) void k_prep_wcat(const float* __restrict__ comp,
                                                   const float* __restrict__ V,
                                                   u16* __restrict__ WcatT) {
    __shared__ float Vt[4][64][65];
    const int k0 = blockIdx.x * 64, n0 = blockIdx.y * 64;   // grid (8, 8)
    const int tn = threadIdx.x & 63;   // n fast -> coalesced V reads
    const int tk = threadIdx.x >> 6;
#pragma unroll
    for (int b = 0; b < 4; ++b)
#pragma unroll
        for (int i = 0; i < 16; ++i) {
            int k = tk + i * 4;
            Vt[b][k][tn] = V[((size_t)b << 18) + (size_t)(k0 + k) * 512 + n0 + tn];
        }
    __syncthreads();
    const int kk = threadIdx.x & 63;   // k fast -> coalesced writes
    const int nq = threadIdx.x >> 6;
    float c[8][4];
#pragma unroll
    for (int r = 0; r < 8; ++r)
#pragma unroll
        for (int b = 0; b < 4; ++b) c[r][b] = comp[r * 4 + b];
    for (int i = 0; i < 16; ++i) {
        int n = nq + i * 4;
        float v0 = Vt[0][kk][n], v1 = Vt[1][kk][n], v2 = Vt[2][kk][n], v3 = Vt[3][kk][n];
#pragma unroll
        for (int r = 0; r < 8; ++r) {
            float s = c[r][0] * v0 + c[r][1] * v1 + c[r][2] * v2 + c[r][3] * v3;
            WcatT[((size_t)(r * 512 + n0 + n) << 9) + k0 + kk] = f2bf(s);
        }
    }
}

// ---------- prep: WelmoT[n][k] = W_elmo[k][n] (LDS transpose) ----------
__global__ __launch_bounds__(256) void k_prep_welmo(const float* __restrict__ W,
                                                    u16* __restrict__ WT) {
    __shared__ float tile[64][65];
    const int k0 = blockIdx.x * 64, n0 = blockIdx.y * 64;
    const int tn = threadIdx.x & 63;
    const int tk = threadIdx.x >> 6;
#pragma unroll
    for (int i = 0; i < 16; ++i) {
        int k = tk + i * 4;
        tile[k][tn] = W[(size_t)(k0 + k) * 256 + n0 + tn];
    }
    __syncthreads();
    const int kk = threadIdx.x & 63;
#pragma unroll
    for (int i = 0; i < 16; ++i) {
        int n = (threadIdx.x >> 6) + i * 4;
        WT[(size_t)(n0 + n) * 3072 + k0 + kk] = f2bf(tile[kk][n]);
    }
}

// ---------- CSR build (dst-keyed) ----------
__global__ __launch_bounds__(256) void k_hist(const int* __restrict__ dst, int* __restrict__ cnt) {
    int e = blockIdx.x * 256 + threadIdx.x;
    atomicAdd(&cnt[dst[e]], 1);
}

__global__ __launch_bounds__(1024) void k_scan(const int* __restrict__ cnt,
                                               int* __restrict__ rowptr,
                                               int* __restrict__ cursor) {
    __shared__ int part[1024];
    int t = threadIdx.x;
    int loc[16];
    int s = 0;
    int base = t * 16;
#pragma unroll
    for (int i = 0; i < 16; ++i) { loc[i] = s; s += cnt[base + i]; }
    part[t] = s;
    __syncthreads();
    for (int off = 1; off < 1024; off <<= 1) {
        int v = (t >= off) ? part[t - off] : 0;
        __syncthreads();
        part[t] += v;
        __syncthreads();
    }
    int excl = (t == 0) ? 0 : part[t - 1];
#pragma unroll
    for (int i = 0; i < 16; ++i) {
        int v = excl + loc[i];
        rowptr[base + i] = v;
        cursor[base + i] = v;
    }
    if (t == 1023) rowptr[TOT] = part[1023];
}

__global__ __launch_bounds__(256) void k_scatter(const int* __restrict__ src,
                                                 const int* __restrict__ dst,
                                                 const int* __restrict__ rel,
                                                 const float* __restrict__ norm,
                                                 int* __restrict__ cursor,
                                                 int* __restrict__ epk,
                                                 float* __restrict__ enorm) {
    int e = blockIdx.x * 256 + threadIdx.x;
    int d = dst[e];
    int pos = atomicAdd(&cursor[d], 1);
    epk[pos] = (src[e] << 3) | rel[e];
    enorm[pos] = norm[e];
}

// ---------- layer GEMM: tile 128Mx256N, BK=64, single-buffer, 3 blocks/CU ----------
// 256 threads (4 waves, 2Mx2N of 64x128); global_load_lds width-16, both-sides XOR swizzle.
// LDS 48 KB (A 16 + B 32) -> 3 blocks/CU fit; launch_bounds(256,3) caps VGPR ~168
// (m97 recipe: occupancy covers the barrier drain). Block swizzle: per XCD 16 M-tiles x
// 16 N-tiles, N fastest -> A-tile L2-resident; A fetched from HBM once chip-wide.
__global__ __launch_bounds__(256, 3) void k_gemm(const u16* __restrict__ A,
                                                 const u16* __restrict__ BT,
                                                 u16* __restrict__ C,
                                                 int K, int lda, int ldb, int ldc) {
    __shared__ __align__(16) u16 As[128 * 64];
    __shared__ __align__(16) u16 Bs[256 * 64];

    const int t = threadIdx.x;
    // grid (128, 16) -> lin 0..2047; nwg % 8 == 0
    const int lin = blockIdx.y * 128 + blockIdx.x;
    const int xcd = lin & 7, q = lin >> 3;          // q in 0..255
    const int tileM = (xcd * 16 + (q >> 4)) * 128;  // 16 M-tiles per XCD
    const int tileN = (q & 15) * 256;               // N fastest

    const int w = t >> 6, l = t & 63;
    const int wr = w >> 1, wc = w & 1;
    const int lo = l & 15, hi = l >> 4;

    const int srow8 = l >> 3;
    const int scol = ((l & 7) ^ srow8) * 8;   // pre-swizzled source 16B-chunk (u16 units)

    f32x4 acc[4][8];
#pragma unroll
    for (int m = 0; m < 4; ++m)
#pragma unroll
        for (int n = 0; n < 8; ++n) acc[m][n] = f32x4{0.f, 0.f, 0.f, 0.f};

    for (int k0 = 0; k0 < K; k0 += 64) {
        // A: 4 instr/wave (rows 0..127), B: 8 instr/wave (rows 0..255)
#pragma unroll
        for (int i = 0; i < 4; ++i) {
            const int rowblk = (w * 4 + i) * 8;            // wave-uniform
            gload16(A + (size_t)(tileM + rowblk + srow8) * lda + k0 + scol, &As[rowblk * 64]);
        }
#pragma unroll
        for (int i = 0; i < 8; ++i) {
            const int rowblk = (w * 8 + i) * 8;            // wave-uniform
            gload16(BT + (size_t)(tileN + rowblk + srow8) * ldb + k0 + scol, &Bs[rowblk * 64]);
        }
        __syncthreads();

#pragma unroll
        for (int kk = 0; kk < 2; ++kk) {
            s16x8 af[4], bf[8];
#pragma unroll
            for (int m = 0; m < 4; ++m) {
                int row = wr * 64 + m * 16 + lo;
                int boff = (row * 128 + kk * 64 + hi * 16) ^ ((row & 7) << 4);
                af[m] = *(const s16x8*)((const char*)As + boff);
            }
#pragma unroll
            for (int n = 0; n < 8; ++n) {
                int row = wc * 128 + n * 16 + lo;
                int boff = (row * 128 + kk * 64 + hi * 16) ^ ((row & 7) << 4);
                bf[n] = *(const s16x8*)((const char*)Bs + boff);
            }
#pragma unroll
            for (int m = 0; m < 4; ++m)
#pragma unroll
                for (int n = 0; n < 8; ++n)
                    acc[m][n] = __builtin_amdgcn_mfma_f32_16x16x32_bf16(
                        af[m], bf[n], acc[m][n], 0, 0, 0);
        }
        __syncthreads();
    }

    // epilogue: C/D layout col=lane&15, row=(lane>>4)*4+reg
#pragma unroll
    for (int m = 0; m < 4; ++m)
#pragma unroll
        for (int n = 0; n < 8; ++n) {
            int col = tileN + wc * 128 + n * 16 + lo;
#pragma unroll
            for (int j = 0; j < 4; ++j) {
                int row = tileM + wr * 64 + m * 16 + hi * 4 + j;
                C[(size_t)row * ldc + col] = f2bf(acc[m][n][j]);
            }
        }
}

// ---------- ELMo GEMM: m97 structure, tile 128Mx256N, BK=64, f32 A via global_load_lds ----------
// writes bf16 partials (per-split f32 accumulate -> RNE round)
__global__ __launch_bounds__(256, 2) void k_gemm_elmo(const float* __restrict__ A,
                                                      const u16* __restrict__ BT,
                                                      u16* __restrict__ Cp) {
    __shared__ __align__(16) float As[128 * 64];   // 128 rows x 64 f32 (256 B/row)
    __shared__ __align__(16) u16   Bs[256 * 64];   // 256 rows x 64 bf16 (128 B/row)

    const int t = threadIdx.x;
    const int tileM = blockIdx.x * 128;
    const int kz = blockIdx.y;
    const int kbeg = kz * (INDIM / EKSPLIT);   // 768 per split, 12 k-steps

    const int w = t >> 6, l = t & 63;
    const int wr = w >> 1, wc = w & 1;
    const int lo = l & 15, hi = l >> 4;

    const int ar = l >> 4;                      // A: row within 4-row group
    const int br = l >> 3;                      // B: row within 8-row group
    const int bcol = ((l & 7) ^ br) * 8;        // B pre-swizzled source chunk (u16 units)

    f32x4 acc[4][8];
#pragma unroll
    for (int m = 0; m < 4; ++m)
#pragma unroll
        for (int n = 0; n < 8; ++n) acc[m][n] = f32x4{0.f, 0.f, 0.f, 0.f};

    for (int ks = 0; ks < 12; ++ks) {
        const int k0 = kbeg + ks * 64;
#pragma unroll
        for (int i = 0; i < 8; ++i) {
            const int RA = (w * 8 + i) * 4;                                   // wave-uniform
            const int ca = (l & 15) ^ ((RA & 15) + ar);                       // source chunk
            gload16(A + (size_t)(tileM + RA + ar) * INDIM + k0 + ca * 4, &As[RA * 64]);
            const int RB = (w * 8 + i) * 8;
            gload16(BT + (size_t)(RB + br) * INDIM + k0 + bcol, &Bs[RB * 64]);
        }
        __syncthreads();

#pragma unroll
        for (int kk = 0; kk < 2; ++kk) {
            s16x8 afr[4], bfr[8];
#pragma unroll
            for (int m = 0; m < 4; ++m) {
                int ra = wr * 64 + m * 16 + lo;
                int x0 = kk * 8 + hi * 2;
                const char* base = (const char*)As + ra * 256;
                f32x4 p = *(const f32x4*)(base + (((x0) ^ (ra & 15)) << 4));
                f32x4 q = *(const f32x4*)(base + (((x0 + 1) ^ (ra & 15)) << 4));
                u32x4 pk = {cvtpk(p[0], p[1]), cvtpk(p[2], p[3]),
                            cvtpk(q[0], q[1]), cvtpk(q[2], q[3])};
                afr[m] = __builtin_bit_cast(s16x8, pk);
            }
#pragma unroll
            for (int n = 0; n < 8; ++n) {
                int rb = wc * 128 + n * 16 + lo;
                int boff = (rb * 128 + kk * 64 + hi * 16) ^ ((rb & 7) << 4);
                bfr[n] = *(const s16x8*)((const char*)Bs + boff);
            }
#pragma unroll
            for (int m = 0; m < 4; ++m)
#pragma unroll
                for (int n = 0; n < 8; ++n)
                    acc[m][n] = __builtin_amdgcn_mfma_f32_16x16x32_bf16(
                        afr[m], bfr[n], acc[m][n], 0, 0, 0);
        }
        __syncthreads();
    }

    u16* cp = Cp + (size_t)kz * TOT * 256;
#pragma unroll
    for (int m = 0; m < 4; ++m)
#pragma unroll
        for (int n = 0; n < 8; ++n) {
            int col = wc * 128 + n * 16 + lo;
#pragma unroll
            for (int j = 0; j < 4; ++j) {
                int row = tileM + wr * 64 + m * 16 + hi * 4 + j;
                cp[(size_t)row * 256 + col] = f2bf(acc[m][n][j]);
            }
        }
}

// ---------- ELMo reduce: xb[:, 0:256] = relu(sum_kz Cp + bias) (bf16 partials) ----------
__global__ __launch_bounds__(256) void k_elmo_reduce(const u16* __restrict__ Cp,
                                                     const float* __restrict__ bias,
                                                     u16* __restrict__ xb) {
    int idx = blockIdx.x * 256 + threadIdx.x;   // 16384*256/4 = 1,048,576 -> grid 4096
    int row = idx >> 6;
    int c4 = (idx & 63) * 4;
    f32x4 s = {0.f, 0.f, 0.f, 0.f};
#pragma unroll
    for (int p = 0; p < EKSPLIT; ++p) {
        u16x4 v = *(const u16x4*)(Cp + (size_t)p * TOT * 256 + (size_t)row * 256 + c4);
#pragma unroll
        for (int j = 0; j < 4; ++j) s[j] += bf2f(v[j]);
    }
    f32x4 bv = *(const f32x4*)(bias + c4);
    u16x4 o;
#pragma unroll
    for (int j = 0; j < 4; ++j) o[j] = f2bf(fmaxf(s[j] + bv[j], 0.f));
    *(u16x4*)(xb + (size_t)row * HID + c4) = o;
}

// ---------- aggregation: wave-per-dst, 16-deep pipelined dwordx4 row reads ----------
__global__ __launch_bounds__(256, 4) void k_agg(const u16* __restrict__ y,
                                                const int* __restrict__ rowptr,
                                                const int* __restrict__ epk,
                                                const float* __restrict__ enorm,
                                                const float* __restrict__ bgcn,
                                                u16* __restrict__ xout) {
    const int wid = (blockIdx.x * 256 + threadIdx.x) >> 6;   // = dst node
    const int l = threadIdx.x & 63;
    const u32x4* yv = (const u32x4*)y;   // y in 16B chunks: (node<<9) + (rel<<6) + lane

    float a[8];
    {
        f32x4 b0 = *(const f32x4*)(bgcn + l * 8);
        f32x4 b1 = *(const f32x4*)(bgcn + l * 8 + 4);
#pragma unroll
        for (int j = 0; j < 4; ++j) { a[j] = b0[j]; a[j + 4] = b1[j]; }
    }

#define ACC1(ee, nq)                                                          \
    {                                                                         \
        u32x4 v_ = yv[(((size_t)((ee) >> 3)) << 9) + (((ee) & 7) << 6) + l];  \
        _Pragma("unroll") for (int j = 0; j < 4; ++j) {                       \
            a[2 * j]     = fmaf((nq), bf2f((u16)v_[j]), a[2 * j]);            \
            a[2 * j + 1] = fmaf((nq), bf2f((u16)(v_[j] >> 16)), a[2 * j + 1]);\
        }                                                                     \
    }

    const int beg = rowptr[wid], end = rowptr[wid + 1];
    int p = beg;
    const int pal = min(end, (beg + 3) & ~3);
    for (; p < pal; ++p) ACC1(epk[p], enorm[p]);

    for (; p + 16 <= end; p += 16) {
        s32x4 e[4];
        f32x4 nn[4];
#pragma unroll
        for (int q4 = 0; q4 < 4; ++q4) {
            e[q4]  = *(const s32x4*)(epk + p + 4 * q4);
            nn[q4] = *(const f32x4*)(enorm + p + 4 * q4);
        }
        u32x4 v[16];
#pragma unroll
        for (int q = 0; q < 16; ++q) {
            int ee = e[q >> 2][q & 3];
            v[q] = yv[(((size_t)(ee >> 3)) << 9) + ((ee & 7) << 6) + l];
        }
#pragma unroll
        for (int q = 0; q < 16; ++q) {
            float nq = nn[q >> 2][q & 3];
#pragma unroll
            for (int j = 0; j < 4; ++j) {
                a[2 * j]     = fmaf(nq, bf2f((u16)v[q][j]), a[2 * j]);
                a[2 * j + 1] = fmaf(nq, bf2f((u16)(v[q][j] >> 16)), a[2 * j + 1]);
            }
        }
    }
    for (; p + 4 <= end; p += 4) {
        s32x4 e4  = *(const s32x4*)(epk + p);
        f32x4 n4  = *(const f32x4*)(enorm + p);
        u32x4 v[4];
#pragma unroll
        for (int q = 0; q < 4; ++q) {
            int ee = e4[q];
            v[q] = yv[(((size_t)(ee >> 3)) << 9) + ((ee & 7) << 6) + l];
        }
#pragma unroll
        for (int q = 0; q < 4; ++q) {
            float nq = n4[q];
#pragma unroll
            for (int j = 0; j < 4; ++j) {
                a[2 * j]     = fmaf(nq, bf2f((u16)v[q][j]), a[2 * j]);
                a[2 * j + 1] = fmaf(nq, bf2f((u16)(v[q][j] >> 16)), a[2 * j + 1]);
            }
        }
    }
    for (; p < end; ++p) ACC1(epk[p], enorm[p]);
#undef ACC1

    u16x8 o;
#pragma unroll
    for (int j = 0; j < 8; ++j) o[j] = f2bf(fmaxf(a[j], 0.f));
    *(u16x8*)(xout + ((size_t)wid << 9) + l * 8) = o;
}

// ---------- final stage 1: per-(graph, 64-node chunk) feature sums (vectorized) ----------
__global__ __launch_bounds__(256) void k_mean1(const u16* __restrict__ xb,
                                               float* __restrict__ part) {
    __shared__ float red[4][512];
    const int g = blockIdx.x >> 4, chunk = blockIdx.x & 15;
    const int fg = threadIdx.x & 63, rg = threadIdx.x >> 6;
    const u16* base =
        xb + ((size_t)(g * NODESPER + chunk * 64 + rg * 16)) * HID + fg * 8;
    float a[8] = {0.f, 0.f, 0.f, 0.f, 0.f, 0.f, 0.f, 0.f};
    for (int rr = 0; rr < 16; ++rr) {
        u16x8 v = *(const u16x8*)(base + (size_t)rr * HID);
#pragma unroll
        for (int j = 0; j < 8; ++j) a[j] += bf2f(v[j]);
    }
#pragma unroll
    for (int j = 0; j < 8; ++j) red[rg][fg * 8 + j] = a[j];
    __syncthreads();
    if (rg == 0) {
#pragma unroll
        for (int j = 0; j < 8; ++j) {
            int f = fg * 8 + j;
            part[(size_t)blockIdx.x * HID + f] =
                red[0][f] + red[1][f] + red[2][f] + red[3][f];
        }
    }
}

// ---------- final stage 2: reduce partials -> mean -> logits -> softmax ----------
__global__ __launch_bounds__(512) void k_final2(const float* __restrict__ part,
                                                const float* __restrict__ W_out,
                                                const float* __restrict__ b_out,
                                                float* __restrict__ out) {
    int g = blockIdx.x, t = threadIdx.x;
    __shared__ float mean_s[512];
    __shared__ float lg[128];
    __shared__ float red[128];
    float s = 0.f;
#pragma unroll
    for (int c = 0; c < 16; ++c) s += part[((size_t)g * 16 + c) * HID + t];
    mean_s[t] = s * (1.0f / (float)NODESPER);
    __syncthreads();
    if (t < NOUT) {
        float a = b_out[t];
        for (int k = 0; k < HID; ++k) a = fmaf(mean_s[k], W_out[(size_t)k * NOUT + t], a);
        lg[t] = a;
        red[t] = a;
    }
    __syncthreads();
    for (int off = 64; off > 0; off >>= 1) {
        if (t < off) red[t] = fmaxf(red[t], red[t + off]);
        __syncthreads();
    }
    float mx = red[0];
    __syncthreads();
    if (t < NOUT) { float e = expf(lg[t] - mx); lg[t] = e; red[t] = e; }
    __syncthreads();
    for (int off = 64; off > 0; off >>= 1) {
        if (t < off) red[t] += red[t + off];
        __syncthreads();
    }
    if (t < NOUT) out[(size_t)g * NOUT + t] = lg[t] / red[0];
}

extern "C" void kernel_launch(void* const* d_in, const int* in_sizes, int n_in,
                              void* d_out, int out_size, void* d_ws, size_t ws_size,
                              hipStream_t stream) {
    const float* h      = (const float*)d_in[0];
    const int*   src    = (const int*)d_in[1];
    const int*   dst    = (const int*)d_in[2];
    const int*   rel    = (const int*)d_in[3];
    const float* norm   = (const float*)d_in[4];
    const float* W_elmo = (const float*)d_in[5];
    const float* b_elmo = (const float*)d_in[6];
    const float* comp   = (const float*)d_in[7];
    const float* V      = (const float*)d_in[8];
    const float* b_gcn  = (const float*)d_in[9];
    const float* W_out  = (const float*)d_in[10];
    const float* b_out  = (const float*)d_in[11];
    float* out = (float*)d_out;

    char* ws = (char*)d_ws;
    u16*   xb     = (u16*)(ws + OFF_XB);
    u16*   y      = (u16*)(ws + OFF_Y);
    u16*   elmoP  = (u16*)(ws + OFF_Y);   // bf16 partials; dead once elmo_reduce completes
    u16*   wcatT  = (u16*)(ws + OFF_WCT);
    u16*   welmoT = (u16*)(ws + OFF_WET);
    int*   cnt    = (int*)(ws + OFF_CNT);
    int*   rowptr = (int*)(ws + OFF_ROWPTR);
    int*   cursor = (int*)(ws + OFF_CURSOR);
    int*   epk    = (int*)(ws + OFF_EPK);
    float* enorm  = (float*)(ws + OFF_ENORM);
    float* part   = (float*)(ws + OFF_PART);

    hipMemsetAsync(cnt, 0, (size_t)TOT * 4, stream);

    k_prep_wcat<<<dim3(8, 8), 256, 0, stream>>>(comp, V, wcatT);
    k_prep_welmo<<<dim3(48, 4), 256, 0, stream>>>(W_elmo, welmoT);

    k_hist<<<EDGES / 256, 256, 0, stream>>>(dst, cnt);
    k_scan<<<1, 1024, 0, stream>>>(cnt, rowptr, cursor);
    k_scatter<<<EDGES / 256, 256, 0, stream>>>(src, dst, rel, norm, cursor, epk, enorm);

    // ELMo: xb[:, 0:256] = relu(h @ W_elmo + b_elmo)  (M=16384, K=3072 split x4, N=256)
    k_gemm_elmo<<<dim3(128, EKSPLIT), 256, 0, stream>>>(h, welmoT, elmoP);
    k_elmo_reduce<<<4096, 256, 0, stream>>>(elmoP, b_elmo, xb);

    for (int L = 0; L < 3; ++L) {
        // y = xb @ Wcat   (M=16384, N=4096; K=256 for layer 1 — xb cols 256.. unread)
        const int Keff = (L == 0) ? 256 : 512;
        k_gemm<<<dim3(128, 16), 256, 0, stream>>>(xb, wcatT, y, Keff, HID, HID,
                                                  NRELS * HID);
        // xb = relu(b_gcn + segment_sum(norm * y[src, r]))  — wave per dst
        k_agg<<<TOT / 4, 256, 0, stream>>>(y, rowptr, epk, enorm, b_gcn, xb);
    }

    k_mean1<<<NGRAPH * 16, 256, 0, stream>>>(xb, part);
    k_final2<<<NGRAPH, 512, 0, stream>>>(part, W_out, b_out, out);
}

// Round 15
// 458.547 us; speedup vs baseline: 2.3506x; 2.3506x over previous
//
#include <hip/hip_runtime.h>

typedef unsigned short u16;
typedef unsigned int   u32;
typedef u16   u16x4 __attribute__((ext_vector_type(4)));
typedef u16   u16x8 __attribute__((ext_vector_type(8)));
typedef short s16x8 __attribute__((ext_vector_type(8)));
typedef u32   u32x4 __attribute__((ext_vector_type(4)));
typedef int   s32x4 __attribute__((ext_vector_type(4)));
typedef float f32x4 __attribute__((ext_vector_type(4)));

// ---------- bf16 helpers (bit-level, RNE) ----------
__device__ __forceinline__ float bf2f(u16 u) {
    u32 x = ((u32)u) << 16;
    return __builtin_bit_cast(float, x);
}
__device__ __forceinline__ u16 f2bf(float f) {
    u32 u = __builtin_bit_cast(u32, f);
    u32 r = u + 0x7FFFu + ((u >> 16) & 1u);
    return (u16)(r >> 16);
}
// packed f32x2 -> bf16x2 (RNE), lo = src0
__device__ __forceinline__ u32 cvtpk(float a, float b) {
    u32 r;
    asm("v_cvt_pk_bf16_f32 %0, %1, %2" : "=v"(r) : "v"(a), "v"(b));
    return r;
}

// async global->LDS, 16B per lane; lds dest is wave-uniform base (HW: base + lane*16)
__device__ __forceinline__ void gload16(const void* g, void* lds) {
    __builtin_amdgcn_global_load_lds((const __attribute__((address_space(1))) void*)g,
                                     (__attribute__((address_space(3))) void*)lds, 16, 0, 0);
}

// ---------- sizes ----------
#define TOT   16384      // BS*N nodes
#define HID   512
#define NRELS 8
#define EDGES 262144
#define INDIM 3072
#define NOUT  128
#define NGRAPH 16
#define NODESPER 1024
#define EKSPLIT 4        // ELMo split-K: 768 per block, 12 k-steps

// workspace layout (16B aligned)
#define OFF_XB     ((size_t)0)                    // u16 [16384][512]   16,777,216 B
#define OFF_Y      (OFF_XB + 16777216)            // u16 [16384][4096] 134,217,728 B (also ELMo bf16 partials [4][16384][256] = 33.5 MB)
#define OFF_WCT    (OFF_Y + 134217728)            // u16 [4096][512]     4,194,304 B
#define OFF_WET    (OFF_WCT + 4194304)            // u16 [256][3072]     1,572,864 B
#define OFF_CNT    (OFF_WET + 1572864)            // int [16384]
#define OFF_ROWPTR (OFF_CNT + 65536)              // int [16385] (+pad)
#define OFF_CURSOR (OFF_ROWPTR + 65552)           // int [16384]
#define OFF_EPK    (OFF_CURSOR + 65536)           // int [262144]
#define OFF_ENORM  (OFF_EPK + 1048576)            // float [262144]
#define OFF_PART   (OFF_ENORM + 1048576)          // float [256][512]

// ---------- prep: WcatT[(r*512+n)][k] = sum_b comp[r,b] * V[b][k][n] ----------
// one block computes one 64x64 (k,n) tile for ALL 8 relations -> V read once (8.4 MB total)
__global__ __launch_bounds__(256) void k_prep_wcat(const float* __restrict__ comp,
                                                   const float* __restrict__ V,
                                                   u16* __restrict__ WcatT) {
    __shared__ float Vt[4][64][65];
    const int k0 = blockIdx.x * 64, n0 = blockIdx.y * 64;   // grid (8, 8)
    const int tn = threadIdx.x & 63;   // n fast -> coalesced V reads
    const int tk = threadIdx.x >> 6;
#pragma unroll
    for (int b = 0; b < 4; ++b)
#pragma unroll
        for (int i = 0; i < 16; ++i) {
            int k = tk + i * 4;
            Vt[b][k][tn] = V[((size_t)b << 18) + (size_t)(k0 + k) * 512 + n0 + tn];
        }
    __syncthreads();
    const int kk = threadIdx.x & 63;   // k fast -> coalesced writes
    const int nq = threadIdx.x >> 6;
    float c[8][4];
#pragma unroll
    for (int r = 0; r < 8; ++r)
#pragma unroll
        for (int b = 0; b < 4; ++b) c[r][b] = comp[r * 4 + b];
    for (int i = 0; i < 16; ++i) {
        int n = nq + i * 4;
        float v0 = Vt[0][kk][n], v1 = Vt[1][kk][n], v2 = Vt[2][kk][n], v3 = Vt[3][kk][n];
#pragma unroll
        for (int r = 0; r < 8; ++r) {
            float s = c[r][0] * v0 + c[r][1] * v1 + c[r][2] * v2 + c[r][3] * v3;
            WcatT[((size_t)(r * 512 + n0 + n) << 9) + k0 + kk] = f2bf(s);
        }
    }
}

// ---------- prep: WelmoT[n][k] = W_elmo[k][n] (LDS transpose) ----------
__global__ __launch_bounds__(256) void k_prep_welmo(const float* __restrict__ W,
                                                    u16* __restrict__ WT) {
    __shared__ float tile[64][65];
    const int k0 = blockIdx.x * 64, n0 = blockIdx.y * 64;
    const int tn = threadIdx.x & 63;
    const int tk = threadIdx.x >> 6;
#pragma unroll
    for (int i = 0; i < 16; ++i) {
        int k = tk + i * 4;
        tile[k][tn] = W[(size_t)(k0 + k) * 256 + n0 + tn];
    }
    __syncthreads();
    const int kk = threadIdx.x & 63;
#pragma unroll
    for (int i = 0; i < 16; ++i) {
        int n = (threadIdx.x >> 6) + i * 4;
        WT[(size_t)(n0 + n) * 3072 + k0 + kk] = f2bf(tile[kk][n]);
    }
}

// ---------- CSR build (dst-keyed) ----------
__global__ __launch_bounds__(256) void k_hist(const int* __restrict__ dst, int* __restrict__ cnt) {
    int e = blockIdx.x * 256 + threadIdx.x;
    atomicAdd(&cnt[dst[e]], 1);
}

__global__ __launch_bounds__(1024) void k_scan(const int* __restrict__ cnt,
                                               int* __restrict__ rowptr,
                                               int* __restrict__ cursor) {
    __shared__ int part[1024];
    int t = threadIdx.x;
    int loc[16];
    int s = 0;
    int base = t * 16;
#pragma unroll
    for (int i = 0; i < 16; ++i) { loc[i] = s; s += cnt[base + i]; }
    part[t] = s;
    __syncthreads();
    for (int off = 1; off < 1024; off <<= 1) {
        int v = (t >= off) ? part[t - off] : 0;
        __syncthreads();
        part[t] += v;
        __syncthreads();
    }
    int excl = (t == 0) ? 0 : part[t - 1];
#pragma unroll
    for (int i = 0; i < 16; ++i) {
        int v = excl + loc[i];
        rowptr[base + i] = v;
        cursor[base + i] = v;
    }
    if (t == 1023) rowptr[TOT] = part[1023];
}

__global__ __launch_bounds__(256) void k_scatter(const int* __restrict__ src,
                                                 const int* __restrict__ dst,
                                                 const int* __restrict__ rel,
                                                 const float* __restrict__ norm,
                                                 int* __restrict__ cursor,
                                                 int* __restrict__ epk,
                                                 float* __restrict__ enorm) {
    int e = blockIdx.x * 256 + threadIdx.x;
    int d = dst[e];
    int pos = atomicAdd(&cursor[d], 1);
    epk[pos] = (src[e] << 3) | rel[e];
    enorm[pos] = norm[e];
}

// ---------- layer GEMM: tile 128Mx256N, BK=64, single-buffer (proven r13 config) ----------
// 256 threads (4 waves, 2Mx2N of 64x128); global_load_lds width-16, both-sides XOR swizzle.
// LDS 48 KB (A 16 + B 32). launch_bounds(256,2) — NOT 3: the 2nd arg is waves/SIMD;
// 3 forces VGPR<=85 and spills the 128-reg accumulator to scratch (r14: 860 MB writes).
// Block swizzle: per XCD 16 M-tiles x 16 N-tiles, N fastest -> A-tile L2-resident.
__global__ __launch_bounds__(256, 2) void k_gemm(const u16* __restrict__ A,
                                                 const u16* __restrict__ BT,
                                                 u16* __restrict__ C,
                                                 int K, int lda, int ldb, int ldc) {
    __shared__ __align__(16) u16 As[128 * 64];
    __shared__ __align__(16) u16 Bs[256 * 64];

    const int t = threadIdx.x;
    // grid (128, 16) -> lin 0..2047; nwg % 8 == 0
    const int lin = blockIdx.y * 128 + blockIdx.x;
    const int xcd = lin & 7, q = lin >> 3;          // q in 0..255
    const int tileM = (xcd * 16 + (q >> 4)) * 128;  // 16 M-tiles per XCD
    const int tileN = (q & 15) * 256;               // N fastest

    const int w = t >> 6, l = t & 63;
    const int wr = w >> 1, wc = w & 1;
    const int lo = l & 15, hi = l >> 4;

    const int srow8 = l >> 3;
    const int scol = ((l & 7) ^ srow8) * 8;   // pre-swizzled source 16B-chunk (u16 units)

    f32x4 acc[4][8];
#pragma unroll
    for (int m = 0; m < 4; ++m)
#pragma unroll
        for (int n = 0; n < 8; ++n) acc[m][n] = f32x4{0.f, 0.f, 0.f, 0.f};

    for (int k0 = 0; k0 < K; k0 += 64) {
        // A: 4 instr/wave (rows 0..127), B: 8 instr/wave (rows 0..255)
#pragma unroll
        for (int i = 0; i < 4; ++i) {
            const int rowblk = (w * 4 + i) * 8;            // wave-uniform
            gload16(A + (size_t)(tileM + rowblk + srow8) * lda + k0 + scol, &As[rowblk * 64]);
        }
#pragma unroll
        for (int i = 0; i < 8; ++i) {
            const int rowblk = (w * 8 + i) * 8;            // wave-uniform
            gload16(BT + (size_t)(tileN + rowblk + srow8) * ldb + k0 + scol, &Bs[rowblk * 64]);
        }
        __syncthreads();

#pragma unroll
        for (int kk = 0; kk < 2; ++kk) {
            s16x8 af[4], bf[8];
#pragma unroll
            for (int m = 0; m < 4; ++m) {
                int row = wr * 64 + m * 16 + lo;
                int boff = (row * 128 + kk * 64 + hi * 16) ^ ((row & 7) << 4);
                af[m] = *(const s16x8*)((const char*)As + boff);
            }
#pragma unroll
            for (int n = 0; n < 8; ++n) {
                int row = wc * 128 + n * 16 + lo;
                int boff = (row * 128 + kk * 64 + hi * 16) ^ ((row & 7) << 4);
                bf[n] = *(const s16x8*)((const char*)Bs + boff);
            }
#pragma unroll
            for (int m = 0; m < 4; ++m)
#pragma unroll
                for (int n = 0; n < 8; ++n)
                    acc[m][n] = __builtin_amdgcn_mfma_f32_16x16x32_bf16(
                        af[m], bf[n], acc[m][n], 0, 0, 0);
        }
        __syncthreads();
    }

    // epilogue: C/D layout col=lane&15, row=(lane>>4)*4+reg
#pragma unroll
    for (int m = 0; m < 4; ++m)
#pragma unroll
        for (int n = 0; n < 8; ++n) {
            int col = tileN + wc * 128 + n * 16 + lo;
#pragma unroll
            for (int j = 0; j < 4; ++j) {
                int row = tileM + wr * 64 + m * 16 + hi * 4 + j;
                C[(size_t)row * ldc + col] = f2bf(acc[m][n][j]);
            }
        }
}

// ---------- ELMo GEMM: m97 structure, tile 128Mx256N, BK=64, f32 A via global_load_lds ----------
// writes bf16 partials (per-split f32 accumulate -> RNE round)
__global__ __launch_bounds__(256, 2) void k_gemm_elmo(const float* __restrict__ A,
                                                      const u16* __restrict__ BT,
                                                      u16* __restrict__ Cp) {
    __shared__ __align__(16) float As[128 * 64];   // 128 rows x 64 f32 (256 B/row)
    __shared__ __align__(16) u16   Bs[256 * 64];   // 256 rows x 64 bf16 (128 B/row)

    const int t = threadIdx.x;
    const int tileM = blockIdx.x * 128;
    const int kz = blockIdx.y;
    const int kbeg = kz * (INDIM / EKSPLIT);   // 768 per split, 12 k-steps

    const int w = t >> 6, l = t & 63;
    const int wr = w >> 1, wc = w & 1;
    const int lo = l & 15, hi = l >> 4;

    const int ar = l >> 4;                      // A: row within 4-row group
    const int br = l >> 3;                      // B: row within 8-row group
    const int bcol = ((l & 7) ^ br) * 8;        // B pre-swizzled source chunk (u16 units)

    f32x4 acc[4][8];
#pragma unroll
    for (int m = 0; m < 4; ++m)
#pragma unroll
        for (int n = 0; n < 8; ++n) acc[m][n] = f32x4{0.f, 0.f, 0.f, 0.f};

    for (int ks = 0; ks < 12; ++ks) {
        const int k0 = kbeg + ks * 64;
#pragma unroll
        for (int i = 0; i < 8; ++i) {
            const int RA = (w * 8 + i) * 4;                                   // wave-uniform
            const int ca = (l & 15) ^ ((RA & 15) + ar);                       // source chunk
            gload16(A + (size_t)(tileM + RA + ar) * INDIM + k0 + ca * 4, &As[RA * 64]);
            const int RB = (w * 8 + i) * 8;
            gload16(BT + (size_t)(RB + br) * INDIM + k0 + bcol, &Bs[RB * 64]);
        }
        __syncthreads();

#pragma unroll
        for (int kk = 0; kk < 2; ++kk) {
            s16x8 afr[4], bfr[8];
#pragma unroll
            for (int m = 0; m < 4; ++m) {
                int ra = wr * 64 + m * 16 + lo;
                int x0 = kk * 8 + hi * 2;
                const char* base = (const char*)As + ra * 256;
                f32x4 p = *(const f32x4*)(base + (((x0) ^ (ra & 15)) << 4));
                f32x4 q = *(const f32x4*)(base + (((x0 + 1) ^ (ra & 15)) << 4));
                u32x4 pk = {cvtpk(p[0], p[1]), cvtpk(p[2], p[3]),
                            cvtpk(q[0], q[1]), cvtpk(q[2], q[3])};
                afr[m] = __builtin_bit_cast(s16x8, pk);
            }
#pragma unroll
            for (int n = 0; n < 8; ++n) {
                int rb = wc * 128 + n * 16 + lo;
                int boff = (rb * 128 + kk * 64 + hi * 16) ^ ((rb & 7) << 4);
                bfr[n] = *(const s16x8*)((const char*)Bs + boff);
            }
#pragma unroll
            for (int m = 0; m < 4; ++m)
#pragma unroll
                for (int n = 0; n < 8; ++n)
                    acc[m][n] = __builtin_amdgcn_mfma_f32_16x16x32_bf16(
                        afr[m], bfr[n], acc[m][n], 0, 0, 0);
        }
        __syncthreads();
    }

    u16* cp = Cp + (size_t)kz * TOT * 256;
#pragma unroll
    for (int m = 0; m < 4; ++m)
#pragma unroll
        for (int n = 0; n < 8; ++n) {
            int col = wc * 128 + n * 16 + lo;
#pragma unroll
            for (int j = 0; j < 4; ++j) {
                int row = tileM + wr * 64 + m * 16 + hi * 4 + j;
                cp[(size_t)row * 256 + col] = f2bf(acc[m][n][j]);
            }
        }
}

// ---------- ELMo reduce: xb[:, 0:256] = relu(sum_kz Cp + bias) (bf16 partials) ----------
__global__ __launch_bounds__(256) void k_elmo_reduce(const u16* __restrict__ Cp,
                                                     const float* __restrict__ bias,
                                                     u16* __restrict__ xb) {
    int idx = blockIdx.x * 256 + threadIdx.x;   // 16384*256/4 = 1,048,576 -> grid 4096
    int row = idx >> 6;
    int c4 = (idx & 63) * 4;
    f32x4 s = {0.f, 0.f, 0.f, 0.f};
#pragma unroll
    for (int p = 0; p < EKSPLIT; ++p) {
        u16x4 v = *(const u16x4*)(Cp + (size_t)p * TOT * 256 + (size_t)row * 256 + c4);
#pragma unroll
        for (int j = 0; j < 4; ++j) s[j] += bf2f(v[j]);
    }
    f32x4 bv = *(const f32x4*)(bias + c4);
    u16x4 o;
#pragma unroll
    for (int j = 0; j < 4; ++j) o[j] = f2bf(fmaxf(s[j] + bv[j], 0.f));
    *(u16x4*)(xb + (size_t)row * HID + c4) = o;
}

// ---------- aggregation: wave-per-dst, 16-deep pipelined dwordx4 row reads ----------
__global__ __launch_bounds__(256, 4) void k_agg(const u16* __restrict__ y,
                                                const int* __restrict__ rowptr,
                                                const int* __restrict__ epk,
                                                const float* __restrict__ enorm,
                                                const float* __restrict__ bgcn,
                                                u16* __restrict__ xout) {
    const int wid = (blockIdx.x * 256 + threadIdx.x) >> 6;   // = dst node
    const int l = threadIdx.x & 63;
    const u32x4* yv = (const u32x4*)y;   // y in 16B chunks: (node<<9) + (rel<<6) + lane

    float a[8];
    {
        f32x4 b0 = *(const f32x4*)(bgcn + l * 8);
        f32x4 b1 = *(const f32x4*)(bgcn + l * 8 + 4);
#pragma unroll
        for (int j = 0; j < 4; ++j) { a[j] = b0[j]; a[j + 4] = b1[j]; }
    }

#define ACC1(ee, nq)                                                          \
    {                                                                         \
        u32x4 v_ = yv[(((size_t)((ee) >> 3)) << 9) + (((ee) & 7) << 6) + l];  \
        _Pragma("unroll") for (int j = 0; j < 4; ++j) {                       \
            a[2 * j]     = fmaf((nq), bf2f((u16)v_[j]), a[2 * j]);            \
            a[2 * j + 1] = fmaf((nq), bf2f((u16)(v_[j] >> 16)), a[2 * j + 1]);\
        }                                                                     \
    }

    const int beg = rowptr[wid], end = rowptr[wid + 1];
    int p = beg;
    const int pal = min(end, (beg + 3) & ~3);
    for (; p < pal; ++p) ACC1(epk[p], enorm[p]);

    for (; p + 16 <= end; p += 16) {
        s32x4 e[4];
        f32x4 nn[4];
#pragma unroll
        for (int q4 = 0; q4 < 4; ++q4) {
            e[q4]  = *(const s32x4*)(epk + p + 4 * q4);
            nn[q4] = *(const f32x4*)(enorm + p + 4 * q4);
        }
        u32x4 v[16];
#pragma unroll
        for (int q = 0; q < 16; ++q) {
            int ee = e[q >> 2][q & 3];
            v[q] = yv[(((size_t)(ee >> 3)) << 9) + ((ee & 7) << 6) + l];
        }
#pragma unroll
        for (int q = 0; q < 16; ++q) {
            float nq = nn[q >> 2][q & 3];
#pragma unroll
            for (int j = 0; j < 4; ++j) {
                a[2 * j]     = fmaf(nq, bf2f((u16)v[q][j]), a[2 * j]);
                a[2 * j + 1] = fmaf(nq, bf2f((u16)(v[q][j] >> 16)), a[2 * j + 1]);
            }
        }
    }
    for (; p + 4 <= end; p += 4) {
        s32x4 e4  = *(const s32x4*)(epk + p);
        f32x4 n4  = *(const f32x4*)(enorm + p);
        u32x4 v[4];
#pragma unroll
        for (int q = 0; q < 4; ++q) {
            int ee = e4[q];
            v[q] = yv[(((size_t)(ee >> 3)) << 9) + ((ee & 7) << 6) + l];
        }
#pragma unroll
        for (int q = 0; q < 4; ++q) {
            float nq = n4[q];
#pragma unroll
            for (int j = 0; j < 4; ++j) {
                a[2 * j]     = fmaf(nq, bf2f((u16)v[q][j]), a[2 * j]);
                a[2 * j + 1] = fmaf(nq, bf2f((u16)(v[q][j] >> 16)), a[2 * j + 1]);
            }
        }
    }
    for (; p < end; ++p) ACC1(epk[p], enorm[p]);
#undef ACC1

    u16x8 o;
#pragma unroll
    for (int j = 0; j < 8; ++j) o[j] = f2bf(fmaxf(a[j], 0.f));
    *(u16x8*)(xout + ((size_t)wid << 9) + l * 8) = o;
}

// ---------- final stage 1: per-(graph, 64-node chunk) feature sums (vectorized) ----------
__global__ __launch_bounds__(256) void k_mean1(const u16* __restrict__ xb,
                                               float* __restrict__ part) {
    __shared__ float red[4][512];
    const int g = blockIdx.x >> 4, chunk = blockIdx.x & 15;
    const int fg = threadIdx.x & 63, rg = threadIdx.x >> 6;
    const u16* base =
        xb + ((size_t)(g * NODESPER + chunk * 64 + rg * 16)) * HID + fg * 8;
    float a[8] = {0.f, 0.f, 0.f, 0.f, 0.f, 0.f, 0.f, 0.f};
    for (int rr = 0; rr < 16; ++rr) {
        u16x8 v = *(const u16x8*)(base + (size_t)rr * HID);
#pragma unroll
        for (int j = 0; j < 8; ++j) a[j] += bf2f(v[j]);
    }
#pragma unroll
    for (int j = 0; j < 8; ++j) red[rg][fg * 8 + j] = a[j];
    __syncthreads();
    if (rg == 0) {
#pragma unroll
        for (int j = 0; j < 8; ++j) {
            int f = fg * 8 + j;
            part[(size_t)blockIdx.x * HID + f] =
                red[0][f] + red[1][f] + red[2][f] + red[3][f];
        }
    }
}

// ---------- final stage 2: reduce partials -> mean -> logits -> softmax ----------
__global__ __launch_bounds__(512) void k_final2(const float* __restrict__ part,
                                                const float* __restrict__ W_out,
                                                const float* __restrict__ b_out,
                                                float* __restrict__ out) {
    int g = blockIdx.x, t = threadIdx.x;
    __shared__ float mean_s[512];
    __shared__ float lg[128];
    __shared__ float red[128];
    float s = 0.f;
#pragma unroll
    for (int c = 0; c < 16; ++c) s += part[((size_t)g * 16 + c) * HID + t];
    mean_s[t] = s * (1.0f / (float)NODESPER);
    __syncthreads();
    if (t < NOUT) {
        float a = b_out[t];
        for (int k = 0; k < HID; ++k) a = fmaf(mean_s[k], W_out[(size_t)k * NOUT + t], a);
        lg[t] = a;
        red[t] = a;
    }
    __syncthreads();
    for (int off = 64; off > 0; off >>= 1) {
        if (t < off) red[t] = fmaxf(red[t], red[t + off]);
        __syncthreads();
    }
    float mx = red[0];
    __syncthreads();
    if (t < NOUT) { float e = expf(lg[t] - mx); lg[t] = e; red[t] = e; }
    __syncthreads();
    for (int off = 64; off > 0; off >>= 1) {
        if (t < off) red[t] += red[t + off];
        __syncthreads();
    }
    if (t < NOUT) out[(size_t)g * NOUT + t] = lg[t] / red[0];
}

extern "C" void kernel_launch(void* const* d_in, const int* in_sizes, int n_in,
                              void* d_out, int out_size, void* d_ws, size_t ws_size,
                              hipStream_t stream) {
    const float* h      = (const float*)d_in[0];
    const int*   src    = (const int*)d_in[1];
    const int*   dst    = (const int*)d_in[2];
    const int*   rel    = (const int*)d_in[3];
    const float* norm   = (const float*)d_in[4];
    const float* W_elmo = (const float*)d_in[5];
    const float* b_elmo = (const float*)d_in[6];
    const float* comp   = (const float*)d_in[7];
    const float* V      = (const float*)d_in[8];
    const float* b_gcn  = (const float*)d_in[9];
    const float* W_out  = (const float*)d_in[10];
    const float* b_out  = (const float*)d_in[11];
    float* out = (float*)d_out;

    char* ws = (char*)d_ws;
    u16*   xb     = (u16*)(ws + OFF_XB);
    u16*   y      = (u16*)(ws + OFF_Y);
    u16*   elmoP  = (u16*)(ws + OFF_Y);   // bf16 partials; dead once elmo_reduce completes
    u16*   wcatT  = (u16*)(ws + OFF_WCT);
    u16*   welmoT = (u16*)(ws + OFF_WET);
    int*   cnt    = (int*)(ws + OFF_CNT);
    int*   rowptr = (int*)(ws + OFF_ROWPTR);
    int*   cursor = (int*)(ws + OFF_CURSOR);
    int*   epk    = (int*)(ws + OFF_EPK);
    float* enorm  = (float*)(ws + OFF_ENORM);
    float* part   = (float*)(ws + OFF_PART);

    hipMemsetAsync(cnt, 0, (size_t)TOT * 4, stream);

    k_prep_wcat<<<dim3(8, 8), 256, 0, stream>>>(comp, V, wcatT);
    k_prep_welmo<<<dim3(48, 4), 256, 0, stream>>>(W_elmo, welmoT);

    k_hist<<<EDGES / 256, 256, 0, stream>>>(dst, cnt);
    k_scan<<<1, 1024, 0, stream>>>(cnt, rowptr, cursor);
    k_scatter<<<EDGES / 256, 256, 0, stream>>>(src, dst, rel, norm, cursor, epk, enorm);

    // ELMo: xb[:, 0:256] = relu(h @ W_elmo + b_elmo)  (M=16384, K=3072 split x4, N=256)
    k_gemm_elmo<<<dim3(128, EKSPLIT), 256, 0, stream>>>(h, welmoT, elmoP);
    k_elmo_reduce<<<4096, 256, 0, stream>>>(elmoP, b_elmo, xb);

    for (int L = 0; L < 3; ++L) {
        // y = xb @ Wcat   (M=16384, N=4096; K=256 for layer 1 — xb cols 256.. unread)
        const int Keff = (L == 0) ? 256 : 512;
        k_gemm<<<dim3(128, 16), 256, 0, stream>>>(xb, wcatT, y, Keff, HID, HID,
                                                  NRELS * HID);
        // xb = relu(b_gcn + segment_sum(norm * y[src, r]))  — wave per dst
        k_agg<<<TOT / 4, 256, 0, stream>>>(y, rowptr, epk, enorm, b_gcn, xb);
    }

    k_mean1<<<NGRAPH * 16, 256, 0, stream>>>(xb, part);
    k_final2<<<NGRAPH, 512, 0, stream>>>(part, W_out, b_out, out);
}